// Round 17
// baseline (199.100 us; speedup 1.0000x reference)
//
#include <hip/hip_runtime.h>
#include <hip/hip_bf16.h>
#include <stdint.h>

#define DIM 1024
#define SEQ 2048
#define TOK 8192   // 4*2048

typedef __hip_bfloat16 bf16;
using bf16x8 = __attribute__((ext_vector_type(8))) short;
using bf16x4 = __attribute__((ext_vector_type(4))) short;
using f32x4  = __attribute__((ext_vector_type(4))) float;

struct __align__(8) bh4 { bf16 a, b, c, d; };

__device__ __forceinline__ void g2lds16(const void* g, void* l) {
    __builtin_amdgcn_global_load_lds(
        (const __attribute__((address_space(1))) void*)g,
        (__attribute__((address_space(3))) void*)l,
        16, 0, 0);
}

// raw HW 2^x (exp2f without -ffast-math goes through OCML fixup code)
__device__ __forceinline__ float hexp2(float x) {
    float r;
    asm("v_exp_f32 %0, %1" : "=v"(r) : "v"(x));
    return r;
}
// packed f32x2 -> bf16x2 RNE in ONE instruction
__device__ __forceinline__ unsigned cvtpk(float lo, float hi) {
    unsigned r;
    asm("v_cvt_pk_bf16_f32 %0, %1, %2" : "=v"(r) : "v"(lo), "v"(hi));
    return r;
}
// raw HW reciprocal (1 ulp; fine for bf16-rounded outputs, l >= 1)
__device__ __forceinline__ float hrcp(float x) {
    float r;
    asm("v_rcp_f32 %0, %1" : "=v"(r) : "v"(x));
    return r;
}

__device__ __forceinline__ short bfb(float f) {
    __hip_bfloat16 h = __float2bfloat16(f);
    return *reinterpret_cast<short*>(&h);
}

// ---------------- cast fp32 -> bf16 (x and the 4 weight matrices) ----------------
__global__ __launch_bounds__(256) void cast_all_kernel(
    const float* __restrict__ x,  const float* __restrict__ wq,
    const float* __restrict__ wk, const float* __restrict__ wv,
    const float* __restrict__ wo, bf16* __restrict__ xb, bf16* __restrict__ wb)
{
    const long idx = (long)blockIdx.x * 256 + threadIdx.x;
    const long e = idx * 4;
    const float* src;
    bf16* dst;
    if (e < 8388608L) { src = x + e; dst = xb + e; }
    else {
        const long j = e - 8388608L;
        const int  w = (int)(j >> 20);
        const long off = j & 1048575L;
        src = ((w == 0) ? wq : (w == 1) ? wk : (w == 2) ? wv : wo) + off;
        dst = wb + ((long)w << 20) + off;
    }
    const float4 v = *(const float4*)src;
    bh4 o;
    o.a = __float2bfloat16(v.x); o.b = __float2bfloat16(v.y);
    o.c = __float2bfloat16(v.z); o.d = __float2bfloat16(v.w);
    *(bh4*)dst = o;
}

// ---------------- C = A @ B^T  (A [M,1024] bf16, B [N,1024] bf16) ----------------
// 128x128 tile, 4 waves x 64x64, acc[4][4], T2 XOR-swizzle (byte ^= (row&7)<<4).
// NEW (v4): DOUBLE-BUFFERED single-barrier K-loop (the scheme proven in attn
// since round 5): stage(t+1 -> buf^1) issued first, then ds_read(buf)+MFMA,
// then ONE __syncthreads per iteration (its vmcnt(0)/lgkmcnt(0) drain covers
// the staging and orders buffer reuse). Barriers halve (32->16); stage latency
// hides under ds_read+MFMA. LDS 64 KB -> 2 blocks/CU (= measured residency).
// NOTE: no launch_bounds occupancy cap — (256,5) forced VGPR=48 -> acc spill
// (round-13). MODE 0: fused QKV; MODE 1: out-proj -> bf16 proj.
template<int MODE>
__global__ __launch_bounds__(256) void gemm_bt_kernel(
    const bf16* __restrict__ A, const bf16* __restrict__ B,
    const float* __restrict__ bias0, const float* __restrict__ bias1,
    const float* __restrict__ bias2,
    bf16* __restrict__ outQ, bf16* __restrict__ outK, bf16* __restrict__ outVt)
{
    __shared__ __align__(16) bf16 As[2][128 * 64];   // 2 x 16 KB, swizzled rows
    __shared__ __align__(16) bf16 Bs[2][128 * 64];   // 2 x 16 KB
    const int tid  = threadIdx.x;
    const int wave = tid >> 6;
    const int lane = tid & 63;
    const int bm = blockIdx.x;
    const int bn = blockIdx.y;
    const int wm = (wave >> 1) * 64;
    const int wn = (wave & 1) * 64;
    const int lcol = lane & 15;
    const int lrow = lane >> 4;
    const int l8 = lane >> 3, l7 = lane & 7;
    const int swz = (l7 ^ l8) * 8;       // pre-swizzled source col (elements)

    f32x4 acc[4][4] = {};

    const bf16* Ab = A + ((long)bm * 128 + wave * 32 + l8) * 1024 + swz;
    const bf16* Bb = B + ((long)bn * 128 + wave * 32 + l8) * 1024 + swz;
    const int woff = (wave * 32) * 128;  // this wave's staging byte offset

    // prologue: stage kt=0 into buffer 0
    #pragma unroll
    for (int i = 0; i < 4; ++i) {
        g2lds16(Ab + (long)i * 8 * 1024, (char*)As[0] + woff + i * 1024);
        g2lds16(Bb + (long)i * 8 * 1024, (char*)Bs[0] + woff + i * 1024);
    }
    __syncthreads();
    for (int t = 0; t < 16; ++t) {
        const int cur = t & 1;
        // stage t+1 into the other buffer: its last readers (iter t-1) finished
        // before the barrier we already passed; loads fly during ds_read+MFMA
        if (t + 1 < 16) {
            const long kt = (long)(t + 1) * 64;
            char* dA = (char*)As[cur ^ 1] + woff;
            char* dB = (char*)Bs[cur ^ 1] + woff;
            #pragma unroll
            for (int i = 0; i < 4; ++i) {
                g2lds16(Ab + (long)i * 8 * 1024 + kt, dA + i * 1024);
                g2lds16(Bb + (long)i * 8 * 1024 + kt, dB + i * 1024);
            }
        }
        const char* Ap = (const char*)As[cur];
        const char* Bp = (const char*)Bs[cur];
        bf16x8 af[4][2], bfr[4][2];
        #pragma unroll
        for (int m = 0; m < 4; ++m) {
            const int row = wm + m * 16 + lcol;
            #pragma unroll
            for (int kk = 0; kk < 2; ++kk) {
                const int off = (row * 128 + kk * 64 + lrow * 16) ^ ((row & 7) << 4);
                af[m][kk] = *(const bf16x8*)(Ap + off);
            }
        }
        #pragma unroll
        for (int n = 0; n < 4; ++n) {
            const int row = wn + n * 16 + lcol;
            #pragma unroll
            for (int kk = 0; kk < 2; ++kk) {
                const int off = (row * 128 + kk * 64 + lrow * 16) ^ ((row & 7) << 4);
                bfr[n][kk] = *(const bf16x8*)(Bp + off);
            }
        }
        #pragma unroll
        for (int kk = 0; kk < 2; ++kk)
            #pragma unroll
            for (int m = 0; m < 4; ++m)
                #pragma unroll
                for (int n = 0; n < 4; ++n)
                    acc[m][n] = __builtin_amdgcn_mfma_f32_16x16x32_bf16(
                        af[m][kk], bfr[n][kk], acc[m][n], 0, 0, 0);
        __syncthreads();   // reads of buf[cur] done + staging of t+1 drained
    }

    const int rbase = lrow * 4;
    if (MODE == 0) {
        const int which = bn >> 3;   // 0=Q 1=K 2=V (block-uniform)
        const float* bias = (which == 0) ? bias0 : (which == 1) ? bias1 : bias2;
        const float QSCALE = 0.125f * 1.44269504089f;  // fold softmax scale into Q
        #pragma unroll
        for (int m = 0; m < 4; ++m) {
            const long gr = (long)bm * 128 + wm + m * 16 + rbase;
            #pragma unroll
            for (int n = 0; n < 4; ++n) {
                const int gc = bn * 128 + wn + n * 16 + lcol;
                const int nn = gc & 1023;
                const float bv_ = bias[nn];
                #pragma unroll
                for (int r = 0; r < 4; ++r) {
                    const long t = gr + r;
                    const float v = acc[m][n][r] + bv_;
                    if (which == 0)      outQ[t * 1024 + nn] = __float2bfloat16(v * QSCALE);
                    else if (which == 1) outK[t * 1024 + nn] = __float2bfloat16(v);
                    else {
                        const long bb = t >> 11;       // batch
                        const long s  = t & 2047;      // seq pos
                        const int  hh = nn >> 6, dh = nn & 63;
                        outVt[((bb * 16 + hh) * 64 + dh) * 2048 + s] = __float2bfloat16(v);
                    }
                }
            }
        }
    } else {
        // proj + bias only, bf16; residual + LN fused into ln_kernel
        #pragma unroll
        for (int m = 0; m < 4; ++m) {
            const long gr = (long)bm * 128 + wm + m * 16 + rbase;
            #pragma unroll
            for (int n = 0; n < 4; ++n) {
                const int gc = bn * 128 + wn + n * 16 + lcol;
                const float bv_ = bias0[gc];
                #pragma unroll
                for (int r = 0; r < 4; ++r) {
                    const long t = gr + r;
                    outQ[t * 1024 + gc] = __float2bfloat16(acc[m][n][r] + bv_);
                }
            }
        }
    }
}

// ---------------- causal flash attention v10 (unchanged from round 16) ---------
__global__ __launch_bounds__(256) void attn_kernel(
    const bf16* __restrict__ Qb, const bf16* __restrict__ Kb,
    const bf16* __restrict__ Vt, bf16* __restrict__ ctx)
{
    __shared__ __align__(16) bf16 Ks[2][2][4096];   // [buf][sub][64 rows x 64 cols]
    __shared__ __align__(16) bf16 Vs[2][2][4096];
    const int tid = threadIdx.x, wv = tid >> 6, lane = tid & 63;
    const int id  = blockIdx.y * 8 + blockIdx.x;    // physical dispatch order (512)
    const int lid = (id & 7) * 64 + (id >> 3);      // XCD-chunked logical id
    const int bh  = lid >> 3;                       // 0..63 (8 heads per XCD)
    const int pr  = lid & 7;                        // 0..7
    const int b = bh >> 4, h = bh & 15;
    const bf16* Qh = Qb + (long)b * SEQ * DIM + h * 64;
    const bf16* Kh = Kb + (long)b * SEQ * DIM + h * 64;
    const bf16* Vh = Vt + (long)bh * 64 * SEQ;
    const int lcol = lane & 15;       // q (C col) / fragment row selector
    const int lrow = lane >> 4;       // 0..3
    const int l8 = lane >> 3, l7 = lane & 7;
    const int swz = (l7 ^ l8) * 8;
    const int kprow = (wv >> 1) * 32 + (l8 >> 2) * 8 + (wv & 1) * 4 + (l8 & 3); // i=0; +16 for i=1
    const bf16* kSrc = Kh + (long)kprow * DIM + swz;            // + (k + i*16)*DIM
    const bf16* vSrc = Vh + (long)(wv * 16 + l8) * SEQ + swz;   // + k + i*8*SEQ

    const bf16x8 ONES = { (short)0x3F80, (short)0x3F80, (short)0x3F80, (short)0x3F80,
                          (short)0x3F80, (short)0x3F80, (short)0x3F80, (short)0x3F80 };

    #pragma unroll
    for (int half = 0; half < 2; ++half) {
        const int qt = half ? (15 - pr) : pr;     // 128-row q tile
        const int qtb = qt * 128;
        const int q0 = qtb + wv * 32;             // this wave's 32 q rows
        bf16x8 qf[2][2];
        #pragma unroll
        for (int g = 0; g < 2; ++g)
            #pragma unroll
            for (int kk = 0; kk < 2; ++kk)
                qf[g][kk] = *(const bf16x8*)&Qh[(long)(q0 + g * 16 + lcol) * DIM + kk * 32 + lrow * 8];

        f32x4 o_acc[2][4] = {};
        f32x4 l_acc[2] = {};
        const int itn = qt + 1;                   // 128-k iterations
        // prologue: stage iteration 0 into buffer 0
        #pragma unroll
        for (int sub = 0; sub < 2; ++sub) {
            char* dK = (char*)Ks[0][sub] + wv * 2048;
            char* dV = (char*)Vs[0][sub] + wv * 2048;
            #pragma unroll
            for (int i = 0; i < 2; ++i) {
                g2lds16(kSrc + (long)(sub * 64 + i * 16) * DIM, dK + i * 1024);
                g2lds16(vSrc + sub * 64 + (long)i * 8 * SEQ, dV + i * 1024);
            }
        }
        __syncthreads();
        for (int it = 0; it < itn; ++it) {
            // prefetch iteration it+1 into the other buffer
            if (it + 1 < itn) {
                const long ko = (long)(it + 1) * 128;
                #pragma unroll
                for (int sub = 0; sub < 2; ++sub) {
                    const bf16* kS = kSrc + (ko + sub * 64) * DIM;
                    const bf16* vS = vSrc + ko + sub * 64;
                    char* dK = (char*)Ks[(it + 1) & 1][sub] + wv * 2048;
                    char* dV = (char*)Vs[(it + 1) & 1][sub] + wv * 2048;
                    #pragma unroll
                    for (int i = 0; i < 2; ++i) {
                        g2lds16(kS + (long)i * 16 * DIM, dK + i * 1024);
                        g2lds16(vS + (long)i * 8 * SEQ, dV + i * 1024);
                    }
                }
            }
            #pragma unroll
            for (int sub = 0; sub < 2; ++sub) {
                const int kbase = it * 128 + sub * 64;
                if (kbase > qtb + 64) continue;    // beyond causal frontier (uniform)
                const char* Kp = (const char*)Ks[it & 1][sub];
                const char* Vp = (const char*)Vs[it & 1][sub];
                // --- S^T sub-tile: mfma(K, Q); K-frag read ONCE, feeds both groups ---
                f32x4 s_acc[2][4] = {};
                __builtin_amdgcn_s_setprio(1);
                #pragma unroll
                for (int n = 0; n < 4; ++n) {
                    const int krow = n * 16 + lcol;
                    #pragma unroll
                    for (int kk = 0; kk < 2; ++kk) {
                        const int off = (krow * 128 + kk * 64 + lrow * 16) ^ ((krow & 7) << 4);
                        bf16x8 kf = *(const bf16x8*)(Kp + off);
                        s_acc[0][n] = __builtin_amdgcn_mfma_f32_16x16x32_bf16(kf, qf[0][kk], s_acc[0][n], 0, 0, 0);
                        s_acc[1][n] = __builtin_amdgcn_mfma_f32_16x16x32_bf16(kf, qf[1][kk], s_acc[1][n], 0, 0, 0);
                    }
                }
                __builtin_amdgcn_s_setprio(0);
                // --- causal mask (diagonal sub-tiles: kbase+64 > qtb); s_acc[g][n][r]
                //     holds actual k = kbase + (n>>1)*32 + lrow*8 + (n&1)*4 + r ---
                if (kbase + 64 > qtb) {
                    #pragma unroll
                    for (int g = 0; g < 2; ++g) {
                        const int qg = q0 + g * 16 + lcol;
                        #pragma unroll
                        for (int n = 0; n < 4; ++n)
                            #pragma unroll
                            for (int r = 0; r < 4; ++r) {
                                const int ka = kbase + ((n >> 1) << 5) + lrow * 8 + ((n & 1) << 2) + r;
                                if (ka > qg) s_acc[g][n][r] = -1e30f;
                            }
                    }
                }
                // --- fixed-m softmax numerator + P pack, per group ---
                __builtin_amdgcn_s_setprio(1);
                #pragma unroll
                for (int g = 0; g < 2; ++g) {
                    #pragma unroll
                    for (int n = 0; n < 4; ++n)
                        #pragma unroll
                        for (int r = 0; r < 4; ++r)
                            s_acc[g][n][r] = hexp2(s_acc[g][n][r]);
                    union { unsigned u[4]; bf16x8 v; } pkA, pkB;
                    pkA.u[0] = cvtpk(s_acc[g][0][0], s_acc[g][0][1]);
                    pkA.u[1] = cvtpk(s_acc[g][0][2], s_acc[g][0][3]);
                    pkA.u[2] = cvtpk(s_acc[g][1][0], s_acc[g][1][1]);
                    pkA.u[3] = cvtpk(s_acc[g][1][2], s_acc[g][1][3]);
                    pkB.u[0] = cvtpk(s_acc[g][2][0], s_acc[g][2][1]);
                    pkB.u[1] = cvtpk(s_acc[g][2][2], s_acc[g][2][3]);
                    pkB.u[2] = cvtpk(s_acc[g][3][0], s_acc[g][3][1]);
                    pkB.u[3] = cvtpk(s_acc[g][3][2], s_acc[g][3][3]);
                    const bf16x8 paA = pkA.v, paB = pkB.v;
                    l_acc[g] = __builtin_amdgcn_mfma_f32_16x16x32_bf16(paA, ONES, l_acc[g], 0, 0, 0);
                    l_acc[g] = __builtin_amdgcn_mfma_f32_16x16x32_bf16(paB, ONES, l_acc[g], 0, 0, 0);
                    // --- PV: V-frags (shared layout) x this group's P ---
                    #pragma unroll
                    for (int d = 0; d < 4; ++d) {
                        const int vrow = d * 16 + lcol;
                        const int offA = (vrow * 128 + lrow * 16) ^ ((vrow & 7) << 4);
                        const int offB = offA ^ 64;   // +64B = k half 2
                        bf16x8 vfA = *(const bf16x8*)(Vp + offA);
                        o_acc[g][d] = __builtin_amdgcn_mfma_f32_16x16x32_bf16(paA, vfA, o_acc[g][d], 0, 0, 0);
                        bf16x8 vfB = *(const bf16x8*)(Vp + offB);
                        o_acc[g][d] = __builtin_amdgcn_mfma_f32_16x16x32_bf16(paB, vfB, o_acc[g][d], 0, 0, 0);
                    }
                }
                __builtin_amdgcn_s_setprio(0);
            }
            __syncthreads();   // readers of buf[it&1] done + staging of it+1 drained
        }
        // --- epilogue: l in same C-layout as o_acc; 1/l via v_rcp (1 ulp) ---
        #pragma unroll
        for (int g = 0; g < 2; ++g) {
            float rl[4];
            #pragma unroll
            for (int r = 0; r < 4; ++r) rl[r] = hrcp(l_acc[g][r]);
            #pragma unroll
            for (int d = 0; d < 4; ++d)
                #pragma unroll
                for (int r = 0; r < 4; ++r) {
                    const float v = o_acc[g][d][r] * rl[r];
                    ctx[(long)(b * SEQ + q0 + g * 16 + lrow * 4 + r) * DIM + h * 64 + d * 16 + lcol] = __float2bfloat16(v);
                }
        }
    }
}

// ---------------- fused residual + row LayerNorm ----------------
// out = LN(proj(bf16) + x(fp32)) * gamma + beta
__global__ __launch_bounds__(256) void ln_kernel(
    const bf16* __restrict__ proj, const float* __restrict__ x,
    float* __restrict__ out,
    const float* __restrict__ gamma, const float* __restrict__ beta)
{
    const long row = blockIdx.x;
    const int tid = threadIdx.x;
    const int c = tid * 4;
    const bh4  pv = *(const bh4*)&proj[row * 1024 + c];
    const float4 xv = *(const float4*)&x[row * 1024 + c];
    float4 v;
    v.x = xv.x + __bfloat162float(pv.a);
    v.y = xv.y + __bfloat162float(pv.b);
    v.z = xv.z + __bfloat162float(pv.c);
    v.w = xv.w + __bfloat162float(pv.d);
    float s  = v.x + v.y + v.z + v.w;
    float s2 = v.x * v.x + v.y * v.y + v.z * v.z + v.w * v.w;
    #pragma unroll
    for (int off = 1; off < 64; off <<= 1) {
        s  += __shfl_xor(s, off);
        s2 += __shfl_xor(s2, off);
    }
    __shared__ float red[8];
    if ((tid & 63) == 0) { red[tid >> 6] = s; red[4 + (tid >> 6)] = s2; }
    __syncthreads();
    s  = red[0] + red[1] + red[2] + red[3];
    s2 = red[4] + red[5] + red[6] + red[7];
    const float mu = s * (1.0f / 1024.0f);
    const float var = fmaxf(s2 * (1.0f / 1024.0f) - mu * mu, 0.0f);
    const float rstd = rsqrtf(var + 1e-5f);
    const float4 g  = *(const float4*)&gamma[c];
    const float4 bb = *(const float4*)&beta[c];
    float4 o;
    o.x = (v.x - mu) * rstd * g.x + bb.x;
    o.y = (v.y - mu) * rstd * g.y + bb.y;
    o.z = (v.z - mu) * rstd * g.z + bb.z;
    o.w = (v.w - mu) * rstd * g.w + bb.w;
    *(float4*)&out[row * 1024 + c] = o;
}

extern "C" void kernel_launch(void* const* d_in, const int* in_sizes, int n_in,
                              void* d_out, int out_size, void* d_ws, size_t ws_size,
                              hipStream_t stream)
{
    const float* x     = (const float*)d_in[0];
    const float* Wq    = (const float*)d_in[1];
    const float* bq    = (const float*)d_in[2];
    const float* Wk    = (const float*)d_in[3];
    const float* bk    = (const float*)d_in[4];
    const float* Wv    = (const float*)d_in[5];
    const float* bv    = (const float*)d_in[6];
    const float* Wo    = (const float*)d_in[7];
    const float* bo    = (const float*)d_in[8];
    const float* gamma = (const float*)d_in[9];
    const float* beta  = (const float*)d_in[10];
    float* out = (float*)d_out;

    char* ws = (char*)d_ws;
    bf16* xb  = (bf16*)(ws);                          // 16 MB  x bf16 [8192,1024]
    bf16* wb  = (bf16*)(ws + (16L << 20));            //  8 MB  Wq,Wk,Wv,Wo bf16 stacked
    bf16* Qb  = (bf16*)(ws + (24L << 20));            // 16 MB  [8192,1024]; reused as proj
    bf16* Kb  = (bf16*)(ws + (40L << 20));            // 16 MB
    bf16* Vt  = (bf16*)(ws + (56L << 20));            // 16 MB  [64][64][2048]
    bf16* ctx = (bf16*)(ws + (72L << 20));            // 16 MB  [8192,1024]
    bf16* proj = Qb;   // Qb is dead after attn; reuse for the out-proj result

    cast_all_kernel<<<12288, 256, 0, stream>>>(x, Wq, Wk, Wv, Wo, xb, wb);
    gemm_bt_kernel<0><<<dim3(64, 24), 256, 0, stream>>>(
        xb, wb, bq, bk, bv, Qb, Kb, Vt);
    attn_kernel<<<dim3(8, 64), 256, 0, stream>>>(Qb, Kb, Vt, ctx);
    gemm_bt_kernel<1><<<dim3(64, 8), 256, 0, stream>>>(
        ctx, wb + 3L * 1048576, bo, nullptr, nullptr, proj, nullptr, nullptr);
    ln_kernel<<<8192, 256, 0, stream>>>(proj, x, out, gamma, beta);
}

// Round 18
// 158.139 us; speedup vs baseline: 1.2590x; 1.2590x over previous
//
#include <hip/hip_runtime.h>
#include <hip/hip_bf16.h>
#include <stdint.h>

#define DIM 1024
#define SEQ 2048
#define TOK 8192   // 4*2048

typedef __hip_bfloat16 bf16;
using bf16x8 = __attribute__((ext_vector_type(8))) short;
using bf16x4 = __attribute__((ext_vector_type(4))) short;
using f32x4  = __attribute__((ext_vector_type(4))) float;

struct __align__(8) bh4 { bf16 a, b, c, d; };

__device__ __forceinline__ void g2lds16(const void* g, void* l) {
    __builtin_amdgcn_global_load_lds(
        (const __attribute__((address_space(1))) void*)g,
        (__attribute__((address_space(3))) void*)l,
        16, 0, 0);
}

// raw HW 2^x (exp2f without -ffast-math goes through OCML fixup code)
__device__ __forceinline__ float hexp2(float x) {
    float r;
    asm("v_exp_f32 %0, %1" : "=v"(r) : "v"(x));
    return r;
}
// packed f32x2 -> bf16x2 RNE in ONE instruction
__device__ __forceinline__ unsigned cvtpk(float lo, float hi) {
    unsigned r;
    asm("v_cvt_pk_bf16_f32 %0, %1, %2" : "=v"(r) : "v"(lo), "v"(hi));
    return r;
}
// raw HW reciprocal (1 ulp; fine for bf16-rounded outputs, l >= 1)
__device__ __forceinline__ float hrcp(float x) {
    float r;
    asm("v_rcp_f32 %0, %1" : "=v"(r) : "v"(x));
    return r;
}

__device__ __forceinline__ short bfb(float f) {
    __hip_bfloat16 h = __float2bfloat16(f);
    return *reinterpret_cast<short*>(&h);
}

// ---------------- cast fp32 -> bf16 (x and the 4 weight matrices) ----------------
__global__ __launch_bounds__(256) void cast_all_kernel(
    const float* __restrict__ x,  const float* __restrict__ wq,
    const float* __restrict__ wk, const float* __restrict__ wv,
    const float* __restrict__ wo, bf16* __restrict__ xb, bf16* __restrict__ wb)
{
    const long idx = (long)blockIdx.x * 256 + threadIdx.x;
    const long e = idx * 4;
    const float* src;
    bf16* dst;
    if (e < 8388608L) { src = x + e; dst = xb + e; }
    else {
        const long j = e - 8388608L;
        const int  w = (int)(j >> 20);
        const long off = j & 1048575L;
        src = ((w == 0) ? wq : (w == 1) ? wk : (w == 2) ? wv : wo) + off;
        dst = wb + ((long)w << 20) + off;
    }
    const float4 v = *(const float4*)src;
    bh4 o;
    o.a = __float2bfloat16(v.x); o.b = __float2bfloat16(v.y);
    o.c = __float2bfloat16(v.z); o.d = __float2bfloat16(v.w);
    *(bh4*)dst = o;
}

// ---------------- C = A @ B^T  (A [M,1024] bf16, B [N,1024] bf16) ----------------
// ROUND-15 STRUCTURE (this family's measured optimum): 128x128 tile, 4 waves x
// 64x64, acc[4][4], T2 XOR-swizzle, SINGLE 32KB buffer, 2 barriers/iter with
// stage(t+1) issued between the reads-done barrier and the MFMA cluster.
// r17 lesson: dbuf (64KB LDS) halves resident blocks -> -38%; do NOT dbuf.
// r13 lesson: launch_bounds reg caps spill acc -> do NOT cap.
// MODE 0: fused QKV; V epilogue packs 4 consecutive-s values into one 8B store.
// MODE 1: out-proj -> bf16 proj (residual+LN fused into ln_kernel).
template<int MODE>
__global__ __launch_bounds__(256) void gemm_bt_kernel(
    const bf16* __restrict__ A, const bf16* __restrict__ B,
    const float* __restrict__ bias0, const float* __restrict__ bias1,
    const float* __restrict__ bias2,
    bf16* __restrict__ outQ, bf16* __restrict__ outK, bf16* __restrict__ outVt)
{
    __shared__ __align__(16) bf16 As[128 * 64];   // 16 KB, swizzled rows of 128B
    __shared__ __align__(16) bf16 Bs[128 * 64];   // 16 KB
    const int tid  = threadIdx.x;
    const int wave = tid >> 6;
    const int lane = tid & 63;
    const int bm = blockIdx.x;
    const int bn = blockIdx.y;
    const int wm = (wave >> 1) * 64;
    const int wn = (wave & 1) * 64;
    const int lcol = lane & 15;
    const int lrow = lane >> 4;
    const int l8 = lane >> 3, l7 = lane & 7;
    const int swz = (l7 ^ l8) * 8;       // pre-swizzled source col (elements)

    f32x4 acc[4][4] = {};

    const bf16* Ab = A + ((long)bm * 128 + wave * 32 + l8) * 1024 + swz;
    const bf16* Bb = B + ((long)bn * 128 + wave * 32 + l8) * 1024 + swz;
    char* AsW = (char*)As + (wave * 32) * 128;
    char* BsW = (char*)Bs + (wave * 32) * 128;

    // prologue: stage kt=0
    #pragma unroll
    for (int i = 0; i < 4; ++i) {
        g2lds16(Ab + (long)i * 8 * 1024, AsW + i * 1024);
        g2lds16(Bb + (long)i * 8 * 1024, BsW + i * 1024);
    }
    for (int kt = 0; kt < 1024; kt += 64) {
        __syncthreads();   // staging for this kt complete (vmcnt drained here)
        bf16x8 af[4][2], bfr[4][2];
        #pragma unroll
        for (int m = 0; m < 4; ++m) {
            const int row = wm + m * 16 + lcol;
            #pragma unroll
            for (int kk = 0; kk < 2; ++kk) {
                const int off = (row * 128 + kk * 64 + lrow * 16) ^ ((row & 7) << 4);
                af[m][kk] = *(const bf16x8*)((const char*)As + off);
            }
        }
        #pragma unroll
        for (int n = 0; n < 4; ++n) {
            const int row = wn + n * 16 + lcol;
            #pragma unroll
            for (int kk = 0; kk < 2; ++kk) {
                const int off = (row * 128 + kk * 64 + lrow * 16) ^ ((row & 7) << 4);
                bfr[n][kk] = *(const bf16x8*)((const char*)Bs + off);
            }
        }
        __syncthreads();   // all waves' LDS reads landed in regs -> safe to overwrite
        if (kt + 64 < 1024) {
            #pragma unroll
            for (int i = 0; i < 4; ++i) {
                g2lds16(Ab + (long)i * 8 * 1024 + kt + 64, AsW + i * 1024);
                g2lds16(Bb + (long)i * 8 * 1024 + kt + 64, BsW + i * 1024);
            }
        }
        #pragma unroll
        for (int kk = 0; kk < 2; ++kk)
            #pragma unroll
            for (int m = 0; m < 4; ++m)
                #pragma unroll
                for (int n = 0; n < 4; ++n)
                    acc[m][n] = __builtin_amdgcn_mfma_f32_16x16x32_bf16(
                        af[m][kk], bfr[n][kk], acc[m][n], 0, 0, 0);
    }

    const int rbase = lrow * 4;
    if (MODE == 0) {
        const int which = bn >> 3;   // 0=Q 1=K 2=V (block-uniform)
        const float* bias = (which == 0) ? bias0 : (which == 1) ? bias1 : bias2;
        const float QSCALE = 0.125f * 1.44269504089f;  // fold softmax scale into Q
        #pragma unroll
        for (int m = 0; m < 4; ++m) {
            const long gr = (long)bm * 128 + wm + m * 16 + rbase;
            #pragma unroll
            for (int n = 0; n < 4; ++n) {
                const int gc = bn * 128 + wn + n * 16 + lcol;
                const int nn = gc & 1023;
                const float bv_ = bias[nn];
                if (which == 2) {
                    // V: 4 r-values are 4 consecutive s of one Vt[bh][dh] row
                    // (gr is 4-aligned; runs never straddle the 2048 boundary)
                    bh4 pk;
                    pk.a = __float2bfloat16(acc[m][n][0] + bv_);
                    pk.b = __float2bfloat16(acc[m][n][1] + bv_);
                    pk.c = __float2bfloat16(acc[m][n][2] + bv_);
                    pk.d = __float2bfloat16(acc[m][n][3] + bv_);
                    const long bb = gr >> 11;      // batch
                    const long s  = gr & 2047;     // seq pos of r=0
                    const int  hh = nn >> 6, dh = nn & 63;
                    *(bh4*)&outVt[((bb * 16 + hh) * 64 + dh) * 2048 + s] = pk;
                } else {
                    #pragma unroll
                    for (int r = 0; r < 4; ++r) {
                        const long t = gr + r;
                        const float v = acc[m][n][r] + bv_;
                        if (which == 0) outQ[t * 1024 + nn] = __float2bfloat16(v * QSCALE);
                        else            outK[t * 1024 + nn] = __float2bfloat16(v);
                    }
                }
            }
        }
    } else {
        // proj + bias only, bf16; residual + LN fused into ln_kernel
        #pragma unroll
        for (int m = 0; m < 4; ++m) {
            const long gr = (long)bm * 128 + wm + m * 16 + rbase;
            #pragma unroll
            for (int n = 0; n < 4; ++n) {
                const int gc = bn * 128 + wn + n * 16 + lcol;
                const float bv_ = bias0[gc];
                #pragma unroll
                for (int r = 0; r < 4; ++r) {
                    const long t = gr + r;
                    outQ[t * 1024 + gc] = __float2bfloat16(acc[m][n][r] + bv_);
                }
            }
        }
    }
}

// ---------------- causal flash attention v10 (unchanged from round 16) ---------
__global__ __launch_bounds__(256) void attn_kernel(
    const bf16* __restrict__ Qb, const bf16* __restrict__ Kb,
    const bf16* __restrict__ Vt, bf16* __restrict__ ctx)
{
    __shared__ __align__(16) bf16 Ks[2][2][4096];   // [buf][sub][64 rows x 64 cols]
    __shared__ __align__(16) bf16 Vs[2][2][4096];
    const int tid = threadIdx.x, wv = tid >> 6, lane = tid & 63;
    const int id  = blockIdx.y * 8 + blockIdx.x;    // physical dispatch order (512)
    const int lid = (id & 7) * 64 + (id >> 3);      // XCD-chunked logical id
    const int bh  = lid >> 3;                       // 0..63 (8 heads per XCD)
    const int pr  = lid & 7;                        // 0..7
    const int b = bh >> 4, h = bh & 15;
    const bf16* Qh = Qb + (long)b * SEQ * DIM + h * 64;
    const bf16* Kh = Kb + (long)b * SEQ * DIM + h * 64;
    const bf16* Vh = Vt + (long)bh * 64 * SEQ;
    const int lcol = lane & 15;       // q (C col) / fragment row selector
    const int lrow = lane >> 4;       // 0..3
    const int l8 = lane >> 3, l7 = lane & 7;
    const int swz = (l7 ^ l8) * 8;
    const int kprow = (wv >> 1) * 32 + (l8 >> 2) * 8 + (wv & 1) * 4 + (l8 & 3); // i=0; +16 for i=1
    const bf16* kSrc = Kh + (long)kprow * DIM + swz;            // + (k + i*16)*DIM
    const bf16* vSrc = Vh + (long)(wv * 16 + l8) * SEQ + swz;   // + k + i*8*SEQ

    const bf16x8 ONES = { (short)0x3F80, (short)0x3F80, (short)0x3F80, (short)0x3F80,
                          (short)0x3F80, (short)0x3F80, (short)0x3F80, (short)0x3F80 };

    #pragma unroll
    for (int half = 0; half < 2; ++half) {
        const int qt = half ? (15 - pr) : pr;     // 128-row q tile
        const int qtb = qt * 128;
        const int q0 = qtb + wv * 32;             // this wave's 32 q rows
        bf16x8 qf[2][2];
        #pragma unroll
        for (int g = 0; g < 2; ++g)
            #pragma unroll
            for (int kk = 0; kk < 2; ++kk)
                qf[g][kk] = *(const bf16x8*)&Qh[(long)(q0 + g * 16 + lcol) * DIM + kk * 32 + lrow * 8];

        f32x4 o_acc[2][4] = {};
        f32x4 l_acc[2] = {};
        const int itn = qt + 1;                   // 128-k iterations
        // prologue: stage iteration 0 into buffer 0
        #pragma unroll
        for (int sub = 0; sub < 2; ++sub) {
            char* dK = (char*)Ks[0][sub] + wv * 2048;
            char* dV = (char*)Vs[0][sub] + wv * 2048;
            #pragma unroll
            for (int i = 0; i < 2; ++i) {
                g2lds16(kSrc + (long)(sub * 64 + i * 16) * DIM, dK + i * 1024);
                g2lds16(vSrc + sub * 64 + (long)i * 8 * SEQ, dV + i * 1024);
            }
        }
        __syncthreads();
        for (int it = 0; it < itn; ++it) {
            // prefetch iteration it+1 into the other buffer
            if (it + 1 < itn) {
                const long ko = (long)(it + 1) * 128;
                #pragma unroll
                for (int sub = 0; sub < 2; ++sub) {
                    const bf16* kS = kSrc + (ko + sub * 64) * DIM;
                    const bf16* vS = vSrc + ko + sub * 64;
                    char* dK = (char*)Ks[(it + 1) & 1][sub] + wv * 2048;
                    char* dV = (char*)Vs[(it + 1) & 1][sub] + wv * 2048;
                    #pragma unroll
                    for (int i = 0; i < 2; ++i) {
                        g2lds16(kS + (long)i * 16 * DIM, dK + i * 1024);
                        g2lds16(vS + (long)i * 8 * SEQ, dV + i * 1024);
                    }
                }
            }
            #pragma unroll
            for (int sub = 0; sub < 2; ++sub) {
                const int kbase = it * 128 + sub * 64;
                if (kbase > qtb + 64) continue;    // beyond causal frontier (uniform)
                const char* Kp = (const char*)Ks[it & 1][sub];
                const char* Vp = (const char*)Vs[it & 1][sub];
                // --- S^T sub-tile: mfma(K, Q); K-frag read ONCE, feeds both groups ---
                f32x4 s_acc[2][4] = {};
                __builtin_amdgcn_s_setprio(1);
                #pragma unroll
                for (int n = 0; n < 4; ++n) {
                    const int krow = n * 16 + lcol;
                    #pragma unroll
                    for (int kk = 0; kk < 2; ++kk) {
                        const int off = (krow * 128 + kk * 64 + lrow * 16) ^ ((krow & 7) << 4);
                        bf16x8 kf = *(const bf16x8*)(Kp + off);
                        s_acc[0][n] = __builtin_amdgcn_mfma_f32_16x16x32_bf16(kf, qf[0][kk], s_acc[0][n], 0, 0, 0);
                        s_acc[1][n] = __builtin_amdgcn_mfma_f32_16x16x32_bf16(kf, qf[1][kk], s_acc[1][n], 0, 0, 0);
                    }
                }
                __builtin_amdgcn_s_setprio(0);
                // --- causal mask (diagonal sub-tiles: kbase+64 > qtb); s_acc[g][n][r]
                //     holds actual k = kbase + (n>>1)*32 + lrow*8 + (n&1)*4 + r ---
                if (kbase + 64 > qtb) {
                    #pragma unroll
                    for (int g = 0; g < 2; ++g) {
                        const int qg = q0 + g * 16 + lcol;
                        #pragma unroll
                        for (int n = 0; n < 4; ++n)
                            #pragma unroll
                            for (int r = 0; r < 4; ++r) {
                                const int ka = kbase + ((n >> 1) << 5) + lrow * 8 + ((n & 1) << 2) + r;
                                if (ka > qg) s_acc[g][n][r] = -1e30f;
                            }
                    }
                }
                // --- fixed-m softmax numerator + P pack, per group ---
                __builtin_amdgcn_s_setprio(1);
                #pragma unroll
                for (int g = 0; g < 2; ++g) {
                    #pragma unroll
                    for (int n = 0; n < 4; ++n)
                        #pragma unroll
                        for (int r = 0; r < 4; ++r)
                            s_acc[g][n][r] = hexp2(s_acc[g][n][r]);
                    union { unsigned u[4]; bf16x8 v; } pkA, pkB;
                    pkA.u[0] = cvtpk(s_acc[g][0][0], s_acc[g][0][1]);
                    pkA.u[1] = cvtpk(s_acc[g][0][2], s_acc[g][0][3]);
                    pkA.u[2] = cvtpk(s_acc[g][1][0], s_acc[g][1][1]);
                    pkA.u[3] = cvtpk(s_acc[g][1][2], s_acc[g][1][3]);
                    pkB.u[0] = cvtpk(s_acc[g][2][0], s_acc[g][2][1]);
                    pkB.u[1] = cvtpk(s_acc[g][2][2], s_acc[g][2][3]);
                    pkB.u[2] = cvtpk(s_acc[g][3][0], s_acc[g][3][1]);
                    pkB.u[3] = cvtpk(s_acc[g][3][2], s_acc[g][3][3]);
                    const bf16x8 paA = pkA.v, paB = pkB.v;
                    l_acc[g] = __builtin_amdgcn_mfma_f32_16x16x32_bf16(paA, ONES, l_acc[g], 0, 0, 0);
                    l_acc[g] = __builtin_amdgcn_mfma_f32_16x16x32_bf16(paB, ONES, l_acc[g], 0, 0, 0);
                    // --- PV: V-frags (shared layout) x this group's P ---
                    #pragma unroll
                    for (int d = 0; d < 4; ++d) {
                        const int vrow = d * 16 + lcol;
                        const int offA = (vrow * 128 + lrow * 16) ^ ((vrow & 7) << 4);
                        const int offB = offA ^ 64;   // +64B = k half 2
                        bf16x8 vfA = *(const bf16x8*)(Vp + offA);
                        o_acc[g][d] = __builtin_amdgcn_mfma_f32_16x16x32_bf16(paA, vfA, o_acc[g][d], 0, 0, 0);
                        bf16x8 vfB = *(const bf16x8*)(Vp + offB);
                        o_acc[g][d] = __builtin_amdgcn_mfma_f32_16x16x32_bf16(paB, vfB, o_acc[g][d], 0, 0, 0);
                    }
                }
                __builtin_amdgcn_s_setprio(0);
            }
            __syncthreads();   // readers of buf[it&1] done + staging of it+1 drained
        }
        // --- epilogue: l in same C-layout as o_acc; 1/l via v_rcp (1 ulp) ---
        #pragma unroll
        for (int g = 0; g < 2; ++g) {
            float rl[4];
            #pragma unroll
            for (int r = 0; r < 4; ++r) rl[r] = hrcp(l_acc[g][r]);
            #pragma unroll
            for (int d = 0; d < 4; ++d)
                #pragma unroll
                for (int r = 0; r < 4; ++r) {
                    const float v = o_acc[g][d][r] * rl[r];
                    ctx[(long)(b * SEQ + q0 + g * 16 + lrow * 4 + r) * DIM + h * 64 + d * 16 + lcol] = __float2bfloat16(v);
                }
        }
    }
}

// ---------------- fused residual + row LayerNorm ----------------
// out = LN(proj(bf16) + x(fp32)) * gamma + beta
__global__ __launch_bounds__(256) void ln_kernel(
    const bf16* __restrict__ proj, const float* __restrict__ x,
    float* __restrict__ out,
    const float* __restrict__ gamma, const float* __restrict__ beta)
{
    const long row = blockIdx.x;
    const int tid = threadIdx.x;
    const int c = tid * 4;
    const bh4  pv = *(const bh4*)&proj[row * 1024 + c];
    const float4 xv = *(const float4*)&x[row * 1024 + c];
    float4 v;
    v.x = xv.x + __bfloat162float(pv.a);
    v.y = xv.y + __bfloat162float(pv.b);
    v.z = xv.z + __bfloat162float(pv.c);
    v.w = xv.w + __bfloat162float(pv.d);
    float s  = v.x + v.y + v.z + v.w;
    float s2 = v.x * v.x + v.y * v.y + v.z * v.z + v.w * v.w;
    #pragma unroll
    for (int off = 1; off < 64; off <<= 1) {
        s  += __shfl_xor(s, off);
        s2 += __shfl_xor(s2, off);
    }
    __shared__ float red[8];
    if ((tid & 63) == 0) { red[tid >> 6] = s; red[4 + (tid >> 6)] = s2; }
    __syncthreads();
    s  = red[0] + red[1] + red[2] + red[3];
    s2 = red[4] + red[5] + red[6] + red[7];
    const float mu = s * (1.0f / 1024.0f);
    const float var = fmaxf(s2 * (1.0f / 1024.0f) - mu * mu, 0.0f);
    const float rstd = rsqrtf(var + 1e-5f);
    const float4 g  = *(const float4*)&gamma[c];
    const float4 bb = *(const float4*)&beta[c];
    float4 o;
    o.x = (v.x - mu) * rstd * g.x + bb.x;
    o.y = (v.y - mu) * rstd * g.y + bb.y;
    o.z = (v.z - mu) * rstd * g.z + bb.z;
    o.w = (v.w - mu) * rstd * g.w + bb.w;
    *(float4*)&out[row * 1024 + c] = o;
}

extern "C" void kernel_launch(void* const* d_in, const int* in_sizes, int n_in,
                              void* d_out, int out_size, void* d_ws, size_t ws_size,
                              hipStream_t stream)
{
    const float* x     = (const float*)d_in[0];
    const float* Wq    = (const float*)d_in[1];
    const float* bq    = (const float*)d_in[2];
    const float* Wk    = (const float*)d_in[3];
    const float* bk    = (const float*)d_in[4];
    const float* Wv    = (const float*)d_in[5];
    const float* bv    = (const float*)d_in[6];
    const float* Wo    = (const float*)d_in[7];
    const float* bo    = (const float*)d_in[8];
    const float* gamma = (const float*)d_in[9];
    const float* beta  = (const float*)d_in[10];
    float* out = (float*)d_out;

    char* ws = (char*)d_ws;
    bf16* xb  = (bf16*)(ws);                          // 16 MB  x bf16 [8192,1024]
    bf16* wb  = (bf16*)(ws + (16L << 20));            //  8 MB  Wq,Wk,Wv,Wo bf16 stacked
    bf16* Qb  = (bf16*)(ws + (24L << 20));            // 16 MB  [8192,1024]; reused as proj
    bf16* Kb  = (bf16*)(ws + (40L << 20));            // 16 MB
    bf16* Vt  = (bf16*)(ws + (56L << 20));            // 16 MB  [64][64][2048]
    bf16* ctx = (bf16*)(ws + (72L << 20));            // 16 MB  [8192,1024]
    bf16* proj = Qb;   // Qb is dead after attn; reuse for the out-proj result

    cast_all_kernel<<<12288, 256, 0, stream>>>(x, Wq, Wk, Wv, Wo, xb, wb);
    gemm_bt_kernel<0><<<dim3(64, 24), 256, 0, stream>>>(
        xb, wb, bq, bk, bv, Qb, Kb, Vt);
    attn_kernel<<<dim3(8, 64), 256, 0, stream>>>(Qb, Kb, Vt, ctx);
    gemm_bt_kernel<1><<<dim3(64, 8), 256, 0, stream>>>(
        ctx, wb + 3L * 1048576, bo, nullptr, nullptr, proj, nullptr, nullptr);
    ln_kernel<<<8192, 256, 0, stream>>>(proj, x, out, gamma, beta);
}